// Round 18
// baseline (127.366 us; speedup 1.0000x reference)
//
#include <hip/hip_runtime.h>

static constexpr int Lc = 512;
static constexpr int Bc = 256;
static constexpr int Tc = 128;

typedef _Float16 half2_t  __attribute__((ext_vector_type(2)));
typedef __fp16   fp16x2_t __attribute__((ext_vector_type(2)));

__device__ __forceinline__ float fdot2(half2_t a, half2_t b, float c) {
  return __builtin_amdgcn_fdot2(a, b, c, false);   // v_dot2_f32_f16
}
__device__ __forceinline__ unsigned pack_h2(float a, float b) {
  union { fp16x2_t h; unsigned u; } cv;
  cv.h = __builtin_amdgcn_cvt_pkrtz(a, b);         // v_cvt_pkrtz_f16_f32
  return cv.u;
}
__device__ __forceinline__ half2_t as_h2(unsigned u) {
  union { unsigned u; half2_t h; } cv;
  cv.u = u;
  return cv.h;
}
// quad_perm [1,0,3,2]: combine the two i-halves (lane pairs).
__device__ __forceinline__ float pair_add(float x) {
  const int y = __builtin_amdgcn_update_dpp(0, __float_as_int(x), 0xB1, 0xf, 0xf, true);
  return x + __int_as_float(y);
}
// quad_perm [2,3,0,1]: lane 4m fetches lane 4m+2's value.
__device__ __forceinline__ float quad_fetch2(float x) {
  const int y = __builtin_amdgcn_update_dpp(0, __float_as_int(x), 0x4E, 0xf, 0xf, true);
  return __int_as_float(y);
}

// R13's proven chain (122us), single delta: score-gather moved to the meet
// kernel (off the fwd chain's sequential wall path). NO setprio (R17: hurt
// ~15us -- both co-resident blocks elevating priority thrashes arbitration),
// prefetch depth stays 3 (R17's depth-2 bundled in the regression).
// fwd chain = blocks 0..255, bwd (transposed) chain = blocks 256..511;
// 256 threads -- the one config where the 32-word E-slice stays in VGPRs.
__launch_bounds__(256, 1)
__global__ void crf_chain(const float* __restrict__ emis,
                          const int* __restrict__ mask,
                          const float* __restrict__ startT,
                          const float* __restrict__ endT,
                          const float* __restrict__ trans,
                          float* __restrict__ pbuf,    // [256][128]
                          float* __restrict__ qbuf,    // [256][128]
                          float* __restrict__ meta)    // [256][4] _,M0,Kf,Kb
{
  const int bid  = blockIdx.x;
  const bool fwd = bid < Bc;
  const int b    = fwd ? bid : bid - Bc;
  const int tid  = threadIdx.x;
  const int jj   = tid >> 1;   // fwd: out col j; bwd: out row i
  const int h    = tid & 1;    // half of the 128-reduction
  const int wid  = tid >> 6;
  const int lane = tid & 63;

  __shared__ __align__(16) unsigned p_lds[2][64];   // packed f16x2
  __shared__ int expo_lds[2];
  __shared__ float wredM[4];

  const size_t strideT = (size_t)Bc * Tc;
  const float* emp = emis + (size_t)b * Tc + jj;

  if (fwd) {
    // E column-slice, packed along i: Eu[q] = (E[h*64+2q][jj], E[h*64+2q+1][jj])
    unsigned Eu[32];
    #pragma unroll
    for (int q = 0; q < 32; ++q) {
      const float e0 = __expf(trans[(h * 64 + 2 * q)     * Tc + jj]);
      const float e1 = __expf(trans[(h * 64 + 2 * q + 1) * Tc + jj]);
      Eu[q] = pack_h2(e0, e1);
    }

    // init t = 0
    const float lp0 = startT[jj] + emp[0];
    float wm = lp0;
    #pragma unroll
    for (int o = 1; o < 64; o <<= 1) wm = fmaxf(wm, __shfl_xor(wm, o));
    if (lane == 0) wredM[wid] = wm;
    __syncthreads();
    const float M0 = fmaxf(fmaxf(wredM[0], wredM[1]), fmaxf(wredM[2], wredM[3]));

    float st = __expf(lp0 - M0);
    {
      const float partner = quad_fetch2(st);
      if ((tid & 3) == 0) p_lds[0][tid >> 2] = pack_h2(st, partner);
      if (tid == 0) expo_lds[0] = 0;
    }

    // em/mask prefetch, depth 3
    float emR0 = emp[1 * strideT], emR1 = emp[2 * strideT], emR2 = emp[3 * strideT];
    int   mR0  = mask[1 * Bc + b], mR1 = mask[2 * Bc + b], mR2 = mask[3 * Bc + b];
    const float* emP = emp + 4 * strideT;   // em[t+3], t=1..255 -> max em[258]
    const int*   mP  = mask + 4 * Bc + b;
    __syncthreads();

    int Ks = 0, buf = 0;
    #pragma unroll 2
    for (int t = 1; t <= 255; ++t) {
      const int e0 = expo_lds[buf];
      const uint4* pv = (const uint4*)&p_lds[buf][h * 32];
      float a0 = 0.f, a1 = 0.f, a2 = 0.f, a3 = 0.f;
      float a4 = 0.f, a5 = 0.f, a6 = 0.f, a7 = 0.f;
      #pragma unroll
      for (int q = 0; q < 8; ++q) {
        const uint4 pq = pv[q];
        if (q & 1) {
          a4 = fdot2(as_h2(pq.x), as_h2(Eu[q * 4 + 0]), a4);
          a5 = fdot2(as_h2(pq.y), as_h2(Eu[q * 4 + 1]), a5);
          a6 = fdot2(as_h2(pq.z), as_h2(Eu[q * 4 + 2]), a6);
          a7 = fdot2(as_h2(pq.w), as_h2(Eu[q * 4 + 3]), a7);
        } else {
          a0 = fdot2(as_h2(pq.x), as_h2(Eu[q * 4 + 0]), a0);
          a1 = fdot2(as_h2(pq.y), as_h2(Eu[q * 4 + 1]), a1);
          a2 = fdot2(as_h2(pq.z), as_h2(Eu[q * 4 + 2]), a2);
          a3 = fdot2(as_h2(pq.w), as_h2(Eu[q * 4 + 3]), a3);
        }
      }
      float s = ((a0 + a1) + (a2 + a3)) + ((a4 + a5) + (a6 + a7));
      s = pair_add(s);

      const float eEm = __expf(emR0);
      const float emNew = emP[0];
      const int   mNew  = mP[0];
      emP += strideT; mP += Bc;

      const float r  = __uint_as_float((unsigned)(127 - e0) << 23);  // 2^-e0
      const float pn = (mR0 ? s * eEm : st) * r;
      Ks += e0;
      st = pn;

      const int nxt = buf ^ 1;
      const float partner = quad_fetch2(pn);
      if ((tid & 3) == 0) p_lds[nxt][tid >> 2] = pack_h2(pn, partner);
      if (tid == 0) {
        int e = (int)((__float_as_uint(pn) >> 23) & 0xff) - 127;
        expo_lds[nxt] = min(max(e, -100), 100);
      }

      emR0 = emR1; emR1 = emR2; emR2 = emNew;
      mR0  = mR1;  mR1  = mR2;  mR2  = mNew;

      asm volatile("s_waitcnt lgkmcnt(0)" ::: "memory");
      __builtin_amdgcn_s_barrier();
      asm volatile("" ::: "memory");
      buf = nxt;
    }

    if (h == 0) pbuf[b * Tc + jj] = st;            // p_255
    if (tid == 0) {
      meta[4 * b + 1] = M0;
      meta[4 * b + 2] = (float)Ks;
    }
  } else {
    // E row-slice, packed along j: Eu[q] = (E[jj][h*64+2q], E[jj][h*64+2q+1])
    unsigned Eu[32];
    #pragma unroll
    for (int q = 0; q < 32; ++q) {
      const float2 tr2 = *(const float2*)&trans[jj * Tc + h * 64 + 2 * q];
      Eu[q] = pack_h2(__expf(tr2.x), __expf(tr2.y));
    }

    // init: q_511 = exp(end); u_511 = eEm_511 .* q_511
    float st = __expf(endT[jj]);
    {
      const float u = st * __expf(emp[511 * strideT]);
      const float partner = quad_fetch2(u);
      if ((tid & 3) == 0) p_lds[0][tid >> 2] = pack_h2(u, partner);
      if (tid == 0) expo_lds[0] = 0;
    }

    // streams, depth 3: m[511..509]; em[510..508]
    int   mR0 = mask[511 * Bc + b], mR1 = mask[510 * Bc + b], mR2 = mask[509 * Bc + b];
    float emR0 = emp[510 * strideT], emR1 = emp[509 * strideT], emR2 = emp[508 * strideT];
    const float* emP = emp + 507 * strideT;   // em[507-k] >= em[252]
    const int*   mP  = mask + 508 * Bc + b;   // m[508-k]  >= m[253]
    __syncthreads();

    int Ks = 0, buf = 0;
    #pragma unroll 2
    for (int k = 0; k < 256; ++k) {            // t = 511 - k
      const int e0 = expo_lds[buf];
      const uint4* pv = (const uint4*)&p_lds[buf][h * 32];
      float a0 = 0.f, a1 = 0.f, a2 = 0.f, a3 = 0.f;
      float a4 = 0.f, a5 = 0.f, a6 = 0.f, a7 = 0.f;
      #pragma unroll
      for (int q = 0; q < 8; ++q) {
        const uint4 pq = pv[q];
        if (q & 1) {
          a4 = fdot2(as_h2(pq.x), as_h2(Eu[q * 4 + 0]), a4);
          a5 = fdot2(as_h2(pq.y), as_h2(Eu[q * 4 + 1]), a5);
          a6 = fdot2(as_h2(pq.z), as_h2(Eu[q * 4 + 2]), a6);
          a7 = fdot2(as_h2(pq.w), as_h2(Eu[q * 4 + 3]), a7);
        } else {
          a0 = fdot2(as_h2(pq.x), as_h2(Eu[q * 4 + 0]), a0);
          a1 = fdot2(as_h2(pq.y), as_h2(Eu[q * 4 + 1]), a1);
          a2 = fdot2(as_h2(pq.z), as_h2(Eu[q * 4 + 2]), a2);
          a3 = fdot2(as_h2(pq.w), as_h2(Eu[q * 4 + 3]), a3);
        }
      }
      float s = ((a0 + a1) + (a2 + a3)) + ((a4 + a5) + (a6 + a7));
      s = pair_add(s);

      const float emNew = emP[0];
      const int   mNew  = mP[0];
      emP -= strideT; mP -= Bc;

      const float r  = __uint_as_float((unsigned)(127 - e0) << 23);
      const float pn = (mR0 ? s : st) * r;     // q_{t-1}
      Ks += e0;
      st = pn;

      const int nxt = buf ^ 1;
      const float u = pn * __expf(emR0);       // u_{t-1} = eEm_{t-1} * q_{t-1}
      const float partner = quad_fetch2(u);
      if ((tid & 3) == 0) p_lds[nxt][tid >> 2] = pack_h2(u, partner);
      if (tid == 0) {
        int e = (int)((__float_as_uint(pn) >> 23) & 0xff) - 127;
        expo_lds[nxt] = min(max(e, -100), 100);
      }

      mR0  = mR1;  mR1  = mR2;  mR2  = mNew;
      emR0 = emR1; emR1 = emR2; emR2 = emNew;

      asm volatile("s_waitcnt lgkmcnt(0)" ::: "memory");
      __builtin_amdgcn_s_barrier();
      asm volatile("" ::: "memory");
      buf = nxt;
    }

    if (h == 0) qbuf[b * Tc + jj] = st;        // q_255
    if (tid == 0) meta[4 * b + 3] = (float)Ks;
  }
}

// Meet kernel: numerator score (moved off the chain wall path) + p.q dot.
__global__ void crf_meet(const float* __restrict__ emis,
                         const int* __restrict__ tags,
                         const int* __restrict__ mask,
                         const float* __restrict__ startT,
                         const float* __restrict__ endT,
                         const float* __restrict__ trans,
                         const float* __restrict__ pbuf,
                         const float* __restrict__ qbuf,
                         const float* __restrict__ meta,
                         float* __restrict__ partial)
{
  const int b    = blockIdx.x;
  const int tid  = threadIdx.x;   // 256
  const int wid  = tid >> 6;
  const int lane = tid & 63;

  __shared__ float wredA[4];
  __shared__ float wredB[4];

  // gold-path score: 2 timesteps per thread
  float v = 0.f, c = 0.f;
  #pragma unroll
  for (int s2 = 0; s2 < 2; ++s2) {
    const int t     = tid + s2 * 256;
    const float mf  = (float)mask[t * Bc + b];
    const int tag_t = tags[t * Bc + b];
    float e = emis[((size_t)t * Bc + b) * Tc + tag_t] * mf;
    if (t >= 1) e += trans[tags[(t - 1) * Bc + b] * Tc + tag_t] * mf;
    v += e; c += mf;
  }
  #pragma unroll
  for (int o = 1; o < 64; o <<= 1) {
    v += __shfl_xor(v, o);
    c += __shfl_xor(c, o);
  }
  if (lane == 0) { wredA[wid] = v; wredB[wid] = c; }
  __syncthreads();

  if (wid == 0) {
    const float2 pp = *(const float2*)&pbuf[b * Tc + 2 * lane];
    const float2 qq = *(const float2*)&qbuf[b * Tc + 2 * lane];
    float d = pp.x * qq.x + pp.y * qq.y;
    #pragma unroll
    for (int o = 1; o < 64; o <<= 1) d += __shfl_xor(d, o);
    if (lane == 0) {
      const float sv = (wredA[0] + wredA[1]) + (wredA[2] + wredA[3]);
      const float sc = (wredB[0] + wredB[1]) + (wredB[2] + wredB[3]);
      const int last_idx = (int)(sc + 0.5f) - 1;
      const float score = sv + startT[tags[b]] + endT[tags[last_idx * Bc + b]];
      const float M0 = meta[4 * b + 1];
      const float Ks = meta[4 * b + 2] + meta[4 * b + 3];
      partial[b] = score - (M0 + Ks * 0.69314718055994531f + __logf(d));
    }
  }
}

// Deterministic final reduction of 256 per-batch llh values -> scalar.
__global__ void crf_reduce(const float* __restrict__ partial, float* __restrict__ out)
{
  const int tid = threadIdx.x;  // 256 threads
  float v = partial[tid];
  #pragma unroll
  for (int o = 1; o < 64; o <<= 1) v += __shfl_xor(v, o);
  __shared__ float ws[4];
  if ((tid & 63) == 0) ws[tid >> 6] = v;
  __syncthreads();
  if (tid == 0) out[0] = (ws[0] + ws[1]) + (ws[2] + ws[3]);
}

extern "C" void kernel_launch(void* const* d_in, const int* in_sizes, int n_in,
                              void* d_out, int out_size, void* d_ws, size_t ws_size,
                              hipStream_t stream)
{
  const float* emis   = (const float*)d_in[0];
  const int*   tags   = (const int*)d_in[1];
  const int*   mask   = (const int*)d_in[2];
  const float* startT = (const float*)d_in[3];
  const float* endT   = (const float*)d_in[4];
  const float* trans  = (const float*)d_in[5];

  float* ws      = (float*)d_ws;
  float* pbuf    = ws;                       // 256*128
  float* qbuf    = ws + 32768;               // 256*128
  float* meta    = ws + 65536;               // 256*4
  float* partial = ws + 66560;               // 256

  crf_chain<<<2 * Bc, 256, 0, stream>>>(emis, mask, startT, endT, trans,
                                        pbuf, qbuf, meta);
  crf_meet<<<Bc, 256, 0, stream>>>(emis, tags, mask, startT, endT, trans,
                                   pbuf, qbuf, meta, partial);
  crf_reduce<<<1, Bc, 0, stream>>>(partial, (float*)d_out);
}

// Round 19
// 124.243 us; speedup vs baseline: 1.0251x; 1.0251x over previous
//
#include <hip/hip_runtime.h>

static constexpr int Lc = 512;
static constexpr int Bc = 256;
static constexpr int Tc = 128;

typedef _Float16 half2_t  __attribute__((ext_vector_type(2)));
typedef __fp16   fp16x2_t __attribute__((ext_vector_type(2)));

__device__ __forceinline__ float fdot2(half2_t a, half2_t b, float c) {
  return __builtin_amdgcn_fdot2(a, b, c, false);   // v_dot2_f32_f16
}
__device__ __forceinline__ unsigned pack_h2(float a, float b) {
  union { fp16x2_t h; unsigned u; } cv;
  cv.h = __builtin_amdgcn_cvt_pkrtz(a, b);         // v_cvt_pkrtz_f16_f32
  return cv.u;
}
__device__ __forceinline__ half2_t as_h2(unsigned u) {
  union { unsigned u; half2_t h; } cv;
  cv.u = u;
  return cv.h;
}
// quad_perm [1,0,3,2]: combine the two i-halves (lane pairs).
__device__ __forceinline__ float pair_add(float x) {
  const int y = __builtin_amdgcn_update_dpp(0, __float_as_int(x), 0xB1, 0xf, 0xf, true);
  return x + __int_as_float(y);
}
// quad_perm [2,3,0,1]: lane 4m fetches lane 4m+2's value.
__device__ __forceinline__ float quad_fetch2(float x) {
  const int y = __builtin_amdgcn_update_dpp(0, __float_as_int(x), 0x4E, 0xf, 0xf, true);
  return __int_as_float(y);
}

// R13 (proven 122us) with ONE delta: the per-step rescale exponent is read
// from the f16 bits of the stored p[0] word (e0 = f16_exponent(p_lds[buf][0]))
// instead of a separate expo_lds pipeline. Deletes the tid==0 exponent
// extract+clamp+ds_write from the critical tail before the barrier; rescale
// stays an exact power of 2 with Ksum tracking the same e0, so the algebra
// is unchanged. First iteration uses e0=0 (same as R13's expo init; avoids
// the un-smoothed p0[0] outlier hazard).
// fwd chain = blocks 0..255, bwd (transposed) chain = blocks 256..511;
// 256 threads/block -- the one config where the 32-word E-slice stays VGPR.
__launch_bounds__(256, 1)
__global__ void crf_llh_kernel(const float* __restrict__ emis,
                               const int* __restrict__ tags,
                               const int* __restrict__ mask,
                               const float* __restrict__ startT,
                               const float* __restrict__ endT,
                               const float* __restrict__ trans,
                               float* __restrict__ pbuf,    // [256][128]
                               float* __restrict__ qbuf,    // [256][128]
                               float* __restrict__ meta)    // [256][4] score,M0,Kf,Kb
{
  const int bid = blockIdx.x;
  const bool fwd = bid < Bc;
  const int b    = fwd ? bid : bid - Bc;
  const int tid  = threadIdx.x;
  const int jj   = tid >> 1;   // fwd: out col j; bwd: out row i
  const int h    = tid & 1;    // half of the 128-reduction
  const int wid  = tid >> 6;
  const int lane = tid & 63;

  __shared__ __align__(16) unsigned p_lds[2][64];   // packed f16x2
  __shared__ float wredA[4];
  __shared__ float wredB[4];

  const size_t strideT = (size_t)Bc * Tc;
  const float* emp = emis + (size_t)b * Tc + jj;

  if (fwd) {
    // ------------- phase 0: numerator (gold-path score) -------------
    float score = 0.0f;  // tid 0 only
    {
      float v = 0.f, c = 0.f;
      #pragma unroll
      for (int s2 = 0; s2 < 2; ++s2) {
        const int t     = tid + s2 * 256;
        const float mf  = (float)mask[t * Bc + b];
        const int tag_t = tags[t * Bc + b];
        float e = emis[((size_t)t * Bc + b) * Tc + tag_t] * mf;
        if (t >= 1) e += trans[tags[(t - 1) * Bc + b] * Tc + tag_t] * mf;
        v += e; c += mf;
      }
      #pragma unroll
      for (int o = 1; o < 64; o <<= 1) {
        v += __shfl_xor(v, o);
        c += __shfl_xor(c, o);
      }
      if (lane == 0) { wredA[wid] = v; wredB[wid] = c; }
      __syncthreads();
      if (tid == 0) {
        const float sv = (wredA[0] + wredA[1]) + (wredA[2] + wredA[3]);
        const float sc = (wredB[0] + wredB[1]) + (wredB[2] + wredB[3]);
        const int last_idx = (int)(sc + 0.5f) - 1;
        score = sv + startT[tags[b]] + endT[tags[last_idx * Bc + b]];
      }
      __syncthreads();
    }

    // E column-slice, f16x2-packed along i
    unsigned Eu[32];
    #pragma unroll
    for (int q = 0; q < 32; ++q) {
      const float e0v = __expf(trans[(h * 64 + 2 * q)     * Tc + jj]);
      const float e1v = __expf(trans[(h * 64 + 2 * q + 1) * Tc + jj]);
      Eu[q] = pack_h2(e0v, e1v);
    }

    // init t = 0
    const float lp0 = startT[jj] + emp[0];
    float wm = lp0;
    #pragma unroll
    for (int o = 1; o < 64; o <<= 1) wm = fmaxf(wm, __shfl_xor(wm, o));
    if (lane == 0) wredA[wid] = wm;
    __syncthreads();
    const float M0 = fmaxf(fmaxf(wredA[0], wredA[1]), fmaxf(wredA[2], wredA[3]));

    float pj = __expf(lp0 - M0);
    {
      const float partner = quad_fetch2(pj);
      if ((tid & 3) == 0) p_lds[0][tid >> 2] = pack_h2(pj, partner);
    }

    float emR0 = emp[1 * strideT], emR1 = emp[2 * strideT], emR2 = emp[3 * strideT];
    int   mR0  = mask[1 * Bc + b], mR1 = mask[2 * Bc + b], mR2 = mask[3 * Bc + b];
    const float* emp3 = emp + 4 * strideT;
    const int*   mp3  = mask + 4 * Bc + b;
    __syncthreads();

    int Ksum = 0, buf = 0;
    #pragma unroll 2
    for (int t = 1; t <= 255; ++t) {
      // rescale exponent from f16 bits of stored p[0] (broadcast b32 read)
      const unsigned w0 = ((const unsigned*)p_lds[buf])[0];
      int e0 = (int)((w0 >> 10) & 31) - 15;
      if (t == 1) e0 = 0;

      const uint4* pv = (const uint4*)&p_lds[buf][h * 32];
      float a0 = 0.f, a1 = 0.f, a2 = 0.f, a3 = 0.f;
      float a4 = 0.f, a5 = 0.f, a6 = 0.f, a7 = 0.f;
      #pragma unroll
      for (int q = 0; q < 8; ++q) {
        const uint4 pq = pv[q];
        if (q & 1) {
          a4 = fdot2(as_h2(pq.x), as_h2(Eu[q * 4 + 0]), a4);
          a5 = fdot2(as_h2(pq.y), as_h2(Eu[q * 4 + 1]), a5);
          a6 = fdot2(as_h2(pq.z), as_h2(Eu[q * 4 + 2]), a6);
          a7 = fdot2(as_h2(pq.w), as_h2(Eu[q * 4 + 3]), a7);
        } else {
          a0 = fdot2(as_h2(pq.x), as_h2(Eu[q * 4 + 0]), a0);
          a1 = fdot2(as_h2(pq.y), as_h2(Eu[q * 4 + 1]), a1);
          a2 = fdot2(as_h2(pq.z), as_h2(Eu[q * 4 + 2]), a2);
          a3 = fdot2(as_h2(pq.w), as_h2(Eu[q * 4 + 3]), a3);
        }
      }
      float s = ((a0 + a1) + (a2 + a3)) + ((a4 + a5) + (a6 + a7));
      s = pair_add(s);

      const float eEm = __expf(emR0);
      const float emNew = emp3[0];           // t+3 <= 258 < 512: always valid
      const int   mNew  = mp3[0];
      emp3 += strideT; mp3 += Bc;

      const float r  = __uint_as_float((unsigned)(127 - e0) << 23);
      const float pn = (mR0 ? s * eEm : pj) * r;
      Ksum += e0;
      pj = pn;

      const int nxt = buf ^ 1;
      const float partner = quad_fetch2(pn);
      if ((tid & 3) == 0) p_lds[nxt][tid >> 2] = pack_h2(pn, partner);

      emR0 = emR1; emR1 = emR2; emR2 = emNew;
      mR0  = mR1;  mR1  = mR2;  mR2  = mNew;

      asm volatile("s_waitcnt lgkmcnt(0)" ::: "memory");
      __builtin_amdgcn_s_barrier();
      asm volatile("" ::: "memory");
      buf = nxt;
    }

    // write p_255 + meta
    if (h == 0) pbuf[b * Tc + jj] = pj;
    if (tid == 0) {
      meta[4 * b + 0] = score;
      meta[4 * b + 1] = M0;
      meta[4 * b + 2] = (float)Ksum;
    }
  } else {
    // ================= BACKWARD: q_255 = S_256^T ... S_511^T end_exp =======
    unsigned Eu[32];
    #pragma unroll
    for (int q = 0; q < 32; ++q) {
      const float2 tr2 = *(const float2*)&trans[jj * Tc + h * 64 + 2 * q];
      Eu[q] = pack_h2(__expf(tr2.x), __expf(tr2.y));
    }

    // init: q_511 = exp(end); u_511 = eEm_511 .* q_511
    float qi = __expf(endT[jj]);
    {
      const float u = qi * __expf(emp[511 * strideT]);
      const float partner = quad_fetch2(u);
      if ((tid & 3) == 0) p_lds[0][tid >> 2] = pack_h2(u, partner);
    }

    int   mR0 = mask[511 * Bc + b], mR1 = mask[510 * Bc + b], mR2 = mask[509 * Bc + b];
    float emR0 = emp[510 * strideT], emR1 = emp[509 * strideT], emR2 = emp[508 * strideT];
    const float* emp3 = emp + 507 * strideT;   // em[507 - k]
    const int*   mp3  = mask + 508 * Bc + b;   // m[508 - k]
    __syncthreads();

    int Ksum = 0, buf = 0;
    #pragma unroll 2
    for (int k = 0; k < 256; ++k) {            // t = 511 - k
      const unsigned w0 = ((const unsigned*)p_lds[buf])[0];
      int e0 = (int)((w0 >> 10) & 31) - 15;
      if (k == 0) e0 = 0;

      const uint4* pv = (const uint4*)&p_lds[buf][h * 32];
      float a0 = 0.f, a1 = 0.f, a2 = 0.f, a3 = 0.f;
      float a4 = 0.f, a5 = 0.f, a6 = 0.f, a7 = 0.f;
      #pragma unroll
      for (int q = 0; q < 8; ++q) {
        const uint4 pq = pv[q];
        if (q & 1) {
          a4 = fdot2(as_h2(pq.x), as_h2(Eu[q * 4 + 0]), a4);
          a5 = fdot2(as_h2(pq.y), as_h2(Eu[q * 4 + 1]), a5);
          a6 = fdot2(as_h2(pq.z), as_h2(Eu[q * 4 + 2]), a6);
          a7 = fdot2(as_h2(pq.w), as_h2(Eu[q * 4 + 3]), a7);
        } else {
          a0 = fdot2(as_h2(pq.x), as_h2(Eu[q * 4 + 0]), a0);
          a1 = fdot2(as_h2(pq.y), as_h2(Eu[q * 4 + 1]), a1);
          a2 = fdot2(as_h2(pq.z), as_h2(Eu[q * 4 + 2]), a2);
          a3 = fdot2(as_h2(pq.w), as_h2(Eu[q * 4 + 3]), a3);
        }
      }
      float s = ((a0 + a1) + (a2 + a3)) + ((a4 + a5) + (a6 + a7));
      s = pair_add(s);

      const float emNew = emp3[0];
      const int   mNew  = mp3[0];
      emp3 -= strideT; mp3 -= Bc;

      const float r  = __uint_as_float((unsigned)(127 - e0) << 23);
      const float pn = (mR0 ? s : qi) * r;     // q_{t-1}
      Ksum += e0;
      qi = pn;

      const int nxt = buf ^ 1;
      const float u = pn * __expf(emR0);       // u_{t-1} = eEm_{t-1} * q_{t-1}
      const float partner = quad_fetch2(u);
      if ((tid & 3) == 0) p_lds[nxt][tid >> 2] = pack_h2(u, partner);

      mR0  = mR1;  mR1  = mR2;  mR2  = mNew;
      emR0 = emR1; emR1 = emR2; emR2 = emNew;

      asm volatile("s_waitcnt lgkmcnt(0)" ::: "memory");
      __builtin_amdgcn_s_barrier();
      asm volatile("" ::: "memory");
      buf = nxt;
    }

    if (h == 0) qbuf[b * Tc + jj] = qi;
    if (tid == 0) meta[4 * b + 3] = (float)Ksum;
  }
}

// Meet: denom_b = M0 + (Kf+Kb)*ln2 + log(p_255 . q_255); partial = score - denom.
__global__ void crf_meet(const float* __restrict__ pbuf,
                         const float* __restrict__ qbuf,
                         const float* __restrict__ meta,
                         float* __restrict__ partial)
{
  const int b = blockIdx.x;
  const int l = threadIdx.x;   // 64
  const float2 pp = *(const float2*)&pbuf[b * Tc + 2 * l];
  const float2 qq = *(const float2*)&qbuf[b * Tc + 2 * l];
  float d = pp.x * qq.x + pp.y * qq.y;
  #pragma unroll
  for (int o = 1; o < 64; o <<= 1) d += __shfl_xor(d, o);
  if (l == 0) {
    const float score = meta[4 * b + 0];
    const float M0    = meta[4 * b + 1];
    const float Ks    = meta[4 * b + 2] + meta[4 * b + 3];
    partial[b] = score - (M0 + Ks * 0.69314718055994531f + __logf(d));
  }
}

// Deterministic final reduction of 256 per-batch llh values -> scalar.
__global__ void crf_reduce(const float* __restrict__ partial, float* __restrict__ out)
{
  const int tid = threadIdx.x;  // 256 threads
  float v = partial[tid];
  #pragma unroll
  for (int o = 1; o < 64; o <<= 1) v += __shfl_xor(v, o);
  __shared__ float ws[4];
  if ((tid & 63) == 0) ws[tid >> 6] = v;
  __syncthreads();
  if (tid == 0) out[0] = (ws[0] + ws[1]) + (ws[2] + ws[3]);
}

extern "C" void kernel_launch(void* const* d_in, const int* in_sizes, int n_in,
                              void* d_out, int out_size, void* d_ws, size_t ws_size,
                              hipStream_t stream)
{
  const float* emis   = (const float*)d_in[0];
  const int*   tags   = (const int*)d_in[1];
  const int*   mask   = (const int*)d_in[2];
  const float* startT = (const float*)d_in[3];
  const float* endT   = (const float*)d_in[4];
  const float* trans  = (const float*)d_in[5];

  float* ws      = (float*)d_ws;
  float* pbuf    = ws;                       // 256*128
  float* qbuf    = ws + 32768;               // 256*128
  float* meta    = ws + 65536;               // 256*4
  float* partial = ws + 66560;               // 256

  crf_llh_kernel<<<2 * Bc, 256, 0, stream>>>(emis, tags, mask, startT, endT,
                                             trans, pbuf, qbuf, meta);
  crf_meet<<<Bc, 64, 0, stream>>>(pbuf, qbuf, meta, partial);
  crf_reduce<<<1, Bc, 0, stream>>>(partial, (float*)d_out);
}

// Round 20
// 121.910 us; speedup vs baseline: 1.0448x; 1.0191x over previous
//
#include <hip/hip_runtime.h>

static constexpr int Lc = 512;
static constexpr int Bc = 256;
static constexpr int Tc = 128;

typedef _Float16 half2_t  __attribute__((ext_vector_type(2)));
typedef __fp16   fp16x2_t __attribute__((ext_vector_type(2)));

__device__ __forceinline__ float fdot2(half2_t a, half2_t b, float c) {
  return __builtin_amdgcn_fdot2(a, b, c, false);   // v_dot2_f32_f16
}
__device__ __forceinline__ unsigned pack_h2(float a, float b) {
  union { fp16x2_t h; unsigned u; } cv;
  cv.h = __builtin_amdgcn_cvt_pkrtz(a, b);         // v_cvt_pkrtz_f16_f32
  return cv.u;
}
__device__ __forceinline__ half2_t as_h2(unsigned u) {
  union { unsigned u; half2_t h; } cv;
  cv.u = u;
  return cv.h;
}
// quad_perm [1,0,3,2]: combine lane pairs (h=0 <-> h=1).
__device__ __forceinline__ float pair_add(float x) {
  const int y = __builtin_amdgcn_update_dpp(0, __float_as_int(x), 0xB1, 0xf, 0xf, true);
  return x + __int_as_float(y);
}
// quad_perm [2,3,0,1]: lane 4m fetches lane 4m+2's value.
__device__ __forceinline__ float quad_fetch2(float x) {
  const int y = __builtin_amdgcn_update_dpp(0, __float_as_int(x), 0x4E, 0xf, 0xf, true);
  return __int_as_float(y);
}

// FINAL (R13 verbatim, measured 122.1us best-of-session):
// Meet-in-the-middle CRF: denom = end^T (S_511...S_1) p_0 is bilinear, so
// forward (p_255, 255 steps) and backward (q_255 = S_256^T..S_511^T end,
// 256 steps) chains run CONCURRENTLY in separate blocks -- the sequential
// wall-clock chain halves vs the single-chain 238us/164us versions.
// Step machinery: 256 thr, j|i = tid>>1, h = tid&1, 32 packed f16x2 E-regs
// (the ONLY array size this allocator keeps VGPR-resident), f16-dot2 GEMV,
// DPP pair-combine, power-of-2 rescale via expo_lds pipeline, raw
// lgkmcnt-only barrier (em prefetches stay in flight), depth-3 prefetch.
// Beaten-alternatives (measured): barrier-free waves +98us, fused-512thr
// +7..9us, setprio +4us, score-move +5us, f16-expo-read +2us.
__launch_bounds__(256, 1)
__global__ void crf_llh_kernel(const float* __restrict__ emis,
                               const int* __restrict__ tags,
                               const int* __restrict__ mask,
                               const float* __restrict__ startT,
                               const float* __restrict__ endT,
                               const float* __restrict__ trans,
                               float* __restrict__ pbuf,    // [256][128]
                               float* __restrict__ qbuf,    // [256][128]
                               float* __restrict__ meta)    // [256][4] score,M0,Kf,Kb
{
  const int bid = blockIdx.x;
  const bool fwd = bid < Bc;
  const int b    = fwd ? bid : bid - Bc;
  const int tid  = threadIdx.x;
  const int j    = tid >> 1;   // fwd: out col j; bwd: out row i
  const int h    = tid & 1;    // half of the 128-reduction
  const int wid  = tid >> 6;
  const int lane = tid & 63;

  __shared__ __align__(16) unsigned p_lds[2][64];   // packed f16x2
  __shared__ int expo_lds[2];
  __shared__ float wredA[4];
  __shared__ float wredB[4];

  const size_t strideT = (size_t)Bc * Tc;
  const float* emp = emis + (size_t)b * Tc + j;

  if (fwd) {
    // ------------- phase 0: numerator (gold-path score) -------------
    float score = 0.0f;  // tid 0 only
    {
      float v = 0.f, c = 0.f;
      #pragma unroll
      for (int s2 = 0; s2 < 2; ++s2) {
        const int t     = tid + s2 * 256;
        const float mf  = (float)mask[t * Bc + b];
        const int tag_t = tags[t * Bc + b];
        float e = emis[((size_t)t * Bc + b) * Tc + tag_t] * mf;
        if (t >= 1) e += trans[tags[(t - 1) * Bc + b] * Tc + tag_t] * mf;
        v += e; c += mf;
      }
      #pragma unroll
      for (int o = 1; o < 64; o <<= 1) {
        v += __shfl_xor(v, o);
        c += __shfl_xor(c, o);
      }
      if (lane == 0) { wredA[wid] = v; wredB[wid] = c; }
      __syncthreads();
      if (tid == 0) {
        const float sv = (wredA[0] + wredA[1]) + (wredA[2] + wredA[3]);
        const float sc = (wredB[0] + wredB[1]) + (wredB[2] + wredB[3]);
        const int last_idx = (int)(sc + 0.5f) - 1;
        score = sv + startT[tags[b]] + endT[tags[last_idx * Bc + b]];
      }
      __syncthreads();
    }

    // E column-slice, f16x2-packed along i: Eu[k] = (E[h*64+2k][j], E[..+1][j])
    unsigned Eu[32];
    #pragma unroll
    for (int q = 0; q < 32; ++q) {
      const float e0 = __expf(trans[(h * 64 + 2 * q)     * Tc + j]);
      const float e1 = __expf(trans[(h * 64 + 2 * q + 1) * Tc + j]);
      Eu[q] = pack_h2(e0, e1);
    }

    // init t = 0
    const float lp0 = startT[j] + emp[0];
    float wm = lp0;
    #pragma unroll
    for (int o = 1; o < 64; o <<= 1) wm = fmaxf(wm, __shfl_xor(wm, o));
    if (lane == 0) wredA[wid] = wm;
    __syncthreads();
    const float M0 = fmaxf(fmaxf(wredA[0], wredA[1]), fmaxf(wredA[2], wredA[3]));

    float pj = __expf(lp0 - M0);
    {
      const float partner = quad_fetch2(pj);
      if ((tid & 3) == 0) p_lds[0][tid >> 2] = pack_h2(pj, partner);
      if (tid == 0) expo_lds[0] = 0;
    }

    float emR0 = emp[1 * strideT], emR1 = emp[2 * strideT], emR2 = emp[3 * strideT];
    int   mR0  = mask[1 * Bc + b], mR1 = mask[2 * Bc + b], mR2 = mask[3 * Bc + b];
    const float* emp3 = emp + 4 * strideT;
    const int*   mp3  = mask + 4 * Bc + b;
    __syncthreads();

    int Ksum = 0, buf = 0;
    #pragma unroll 2
    for (int t = 1; t <= 255; ++t) {
      const int e0 = expo_lds[buf];
      const uint4* pv = (const uint4*)&p_lds[buf][h * 32];
      float a0 = 0.f, a1 = 0.f, a2 = 0.f, a3 = 0.f;
      float a4 = 0.f, a5 = 0.f, a6 = 0.f, a7 = 0.f;
      #pragma unroll
      for (int q = 0; q < 8; ++q) {
        const uint4 pq = pv[q];
        if (q & 1) {
          a4 = fdot2(as_h2(pq.x), as_h2(Eu[q * 4 + 0]), a4);
          a5 = fdot2(as_h2(pq.y), as_h2(Eu[q * 4 + 1]), a5);
          a6 = fdot2(as_h2(pq.z), as_h2(Eu[q * 4 + 2]), a6);
          a7 = fdot2(as_h2(pq.w), as_h2(Eu[q * 4 + 3]), a7);
        } else {
          a0 = fdot2(as_h2(pq.x), as_h2(Eu[q * 4 + 0]), a0);
          a1 = fdot2(as_h2(pq.y), as_h2(Eu[q * 4 + 1]), a1);
          a2 = fdot2(as_h2(pq.z), as_h2(Eu[q * 4 + 2]), a2);
          a3 = fdot2(as_h2(pq.w), as_h2(Eu[q * 4 + 3]), a3);
        }
      }
      float s = ((a0 + a1) + (a2 + a3)) + ((a4 + a5) + (a6 + a7));
      s = pair_add(s);

      const float eEm = __expf(emR0);
      const float emNew = emp3[0];           // t+3 <= 258 < 512: always valid
      const int   mNew  = mp3[0];
      emp3 += strideT; mp3 += Bc;

      const float r  = __uint_as_float((unsigned)(127 - e0) << 23);
      const float pn = (mR0 ? s * eEm : pj) * r;
      Ksum += e0;
      pj = pn;

      const int nxt = buf ^ 1;
      const float partner = quad_fetch2(pn);
      if ((tid & 3) == 0) p_lds[nxt][tid >> 2] = pack_h2(pn, partner);
      if (tid == 0) {
        int e = (int)((__float_as_uint(pn) >> 23) & 0xff) - 127;
        expo_lds[nxt] = min(max(e, -100), 100);
      }

      emR0 = emR1; emR1 = emR2; emR2 = emNew;
      mR0  = mR1;  mR1  = mR2;  mR2  = mNew;

      asm volatile("s_waitcnt lgkmcnt(0)" ::: "memory");
      __builtin_amdgcn_s_barrier();
      asm volatile("" ::: "memory");
      buf = nxt;
    }

    // write p_255 + meta
    if (h == 0) pbuf[b * Tc + j] = pj;
    if (tid == 0) {
      meta[4 * b + 0] = score;
      meta[4 * b + 1] = M0;
      meta[4 * b + 2] = (float)Ksum;
    }
  } else {
    // ================= BACKWARD: q_255 = S_256^T ... S_511^T end_exp =======
    // E row-slice: Eu[k] = (E[i][h*64+2k], E[i][h*64+2k+1]), i = j (tid>>1)
    unsigned Eu[32];
    #pragma unroll
    for (int q = 0; q < 32; ++q) {
      const float2 tr2 = *(const float2*)&trans[j * Tc + h * 64 + 2 * q];
      Eu[q] = pack_h2(__expf(tr2.x), __expf(tr2.y));
    }

    // init: q_511 = exp(end); u_511 = eEm_511 .* q_511
    float qi = __expf(endT[j]);
    {
      const float u = qi * __expf(emp[511 * strideT]);
      const float partner = quad_fetch2(u);
      if ((tid & 3) == 0) p_lds[0][tid >> 2] = pack_h2(u, partner);
      if (tid == 0) expo_lds[0] = 0;
    }

    // mask stream: m[511], m[510], m[509]; em stream (for u at t-1):
    // em[510], em[509], em[508]
    int   mR0 = mask[511 * Bc + b], mR1 = mask[510 * Bc + b], mR2 = mask[509 * Bc + b];
    float emR0 = emp[510 * strideT], emR1 = emp[509 * strideT], emR2 = emp[508 * strideT];
    const float* emp3 = emp + 507 * strideT;   // em[507 - k]
    const int*   mp3  = mask + 508 * Bc + b;   // m[508 - k]
    __syncthreads();

    int Ksum = 0, buf = 0;
    #pragma unroll 2
    for (int k = 0; k < 256; ++k) {            // t = 511 - k
      const int e0 = expo_lds[buf];
      const uint4* pv = (const uint4*)&p_lds[buf][h * 32];
      float a0 = 0.f, a1 = 0.f, a2 = 0.f, a3 = 0.f;
      float a4 = 0.f, a5 = 0.f, a6 = 0.f, a7 = 0.f;
      #pragma unroll
      for (int q = 0; q < 8; ++q) {
        const uint4 pq = pv[q];
        if (q & 1) {
          a4 = fdot2(as_h2(pq.x), as_h2(Eu[q * 4 + 0]), a4);
          a5 = fdot2(as_h2(pq.y), as_h2(Eu[q * 4 + 1]), a5);
          a6 = fdot2(as_h2(pq.z), as_h2(Eu[q * 4 + 2]), a6);
          a7 = fdot2(as_h2(pq.w), as_h2(Eu[q * 4 + 3]), a7);
        } else {
          a0 = fdot2(as_h2(pq.x), as_h2(Eu[q * 4 + 0]), a0);
          a1 = fdot2(as_h2(pq.y), as_h2(Eu[q * 4 + 1]), a1);
          a2 = fdot2(as_h2(pq.z), as_h2(Eu[q * 4 + 2]), a2);
          a3 = fdot2(as_h2(pq.w), as_h2(Eu[q * 4 + 3]), a3);
        }
      }
      float s = ((a0 + a1) + (a2 + a3)) + ((a4 + a5) + (a6 + a7));
      s = pair_add(s);

      // loads always in-bounds: em[507-k] >= em[252], m[508-k] >= m[253]
      const float emNew = emp3[0];
      const int   mNew  = mp3[0];
      emp3 -= strideT; mp3 -= Bc;

      const float r  = __uint_as_float((unsigned)(127 - e0) << 23);
      const float pn = (mR0 ? s : qi) * r;     // q_{t-1}
      Ksum += e0;
      qi = pn;

      const int nxt = buf ^ 1;
      const float u = pn * __expf(emR0);       // u_{t-1} = eEm_{t-1} * q_{t-1}
      const float partner = quad_fetch2(u);
      if ((tid & 3) == 0) p_lds[nxt][tid >> 2] = pack_h2(u, partner);
      if (tid == 0) {
        int e = (int)((__float_as_uint(pn) >> 23) & 0xff) - 127;
        expo_lds[nxt] = min(max(e, -100), 100);
      }

      mR0  = mR1;  mR1  = mR2;  mR2  = mNew;
      emR0 = emR1; emR1 = emR2; emR2 = emNew;

      asm volatile("s_waitcnt lgkmcnt(0)" ::: "memory");
      __builtin_amdgcn_s_barrier();
      asm volatile("" ::: "memory");
      buf = nxt;
    }

    if (h == 0) qbuf[b * Tc + j] = qi;
    if (tid == 0) meta[4 * b + 3] = (float)Ksum;
  }
}

// Meet: denom_b = M0 + (Kf+Kb)*ln2 + log(p_255 . q_255); partial = score - denom.
__global__ void crf_meet(const float* __restrict__ pbuf,
                         const float* __restrict__ qbuf,
                         const float* __restrict__ meta,
                         float* __restrict__ partial)
{
  const int b = blockIdx.x;
  const int l = threadIdx.x;   // 64
  const float2 pp = *(const float2*)&pbuf[b * Tc + 2 * l];
  const float2 qq = *(const float2*)&qbuf[b * Tc + 2 * l];
  float d = pp.x * qq.x + pp.y * qq.y;
  #pragma unroll
  for (int o = 1; o < 64; o <<= 1) d += __shfl_xor(d, o);
  if (l == 0) {
    const float score = meta[4 * b + 0];
    const float M0    = meta[4 * b + 1];
    const float Ks    = meta[4 * b + 2] + meta[4 * b + 3];
    partial[b] = score - (M0 + Ks * 0.69314718055994531f + __logf(d));
  }
}

// Deterministic final reduction of 256 per-batch llh values -> scalar.
__global__ void crf_reduce(const float* __restrict__ partial, float* __restrict__ out)
{
  const int tid = threadIdx.x;  // 256 threads
  float v = partial[tid];
  #pragma unroll
  for (int o = 1; o < 64; o <<= 1) v += __shfl_xor(v, o);
  __shared__ float ws[4];
  if ((tid & 63) == 0) ws[tid >> 6] = v;
  __syncthreads();
  if (tid == 0) out[0] = (ws[0] + ws[1]) + (ws[2] + ws[3]);
}

extern "C" void kernel_launch(void* const* d_in, const int* in_sizes, int n_in,
                              void* d_out, int out_size, void* d_ws, size_t ws_size,
                              hipStream_t stream)
{
  const float* emis   = (const float*)d_in[0];
  const int*   tags   = (const int*)d_in[1];
  const int*   mask   = (const int*)d_in[2];
  const float* startT = (const float*)d_in[3];
  const float* endT   = (const float*)d_in[4];
  const float* trans  = (const float*)d_in[5];

  float* ws      = (float*)d_ws;
  float* pbuf    = ws;                       // 256*128
  float* qbuf    = ws + 32768;               // 256*128
  float* meta    = ws + 65536;               // 256*4
  float* partial = ws + 66560;               // 256

  crf_llh_kernel<<<2 * Bc, 256, 0, stream>>>(emis, tags, mask, startT, endT,
                                             trans, pbuf, qbuf, meta);
  crf_meet<<<Bc, 64, 0, stream>>>(pbuf, qbuf, meta, partial);
  crf_reduce<<<1, Bc, 0, stream>>>(partial, (float*)d_out);
}